// Round 3
// baseline (456.514 us; speedup 1.0000x reference)
//
#include <hip/hip_runtime.h>
#include <hip/hip_bf16.h>
#include <stdint.h>

#define B_ROWS 8192
#define N_TOT  16384
#define D_DIM  128
// sqrt(1/0.07): fold temperature into the normalized features so
// (s*f_i)·(s*f_j) = sim/TEMP and the epilogue stores acc directly.
#define SCALE_SQRT_INVT 3.7796447300922722f

typedef __bf16 bf16x8 __attribute__((ext_vector_type(8)));
typedef float  f32x4  __attribute__((ext_vector_type(4)));

// ---------------- Kernel 1: normalize rows of concat(q,k) -> bf16 ----------
__global__ void simclr_norm_kernel(const float* __restrict__ q,
                                   const float* __restrict__ k,
                                   unsigned int* __restrict__ fb) {
    const int lane = threadIdx.x & 63;
    const int row  = blockIdx.x * 4 + (threadIdx.x >> 6);
    const float* src = (row < B_ROWS) ? (q + (size_t)row * D_DIM)
                                      : (k + (size_t)(row - B_ROWS) * D_DIM);
    float2 v = ((const float2*)src)[lane];
    float s = v.x * v.x + v.y * v.y;
#pragma unroll
    for (int off = 32; off > 0; off >>= 1) s += __shfl_xor(s, off);
    float rn = SCALE_SQRT_INVT / fmaxf(sqrtf(s), 1e-12f);
    union { __bf16 h[2]; unsigned int u; } pk;
    pk.h[0] = (__bf16)(v.x * rn);
    pk.h[1] = (__bf16)(v.y * rn);
    fb[(size_t)row * 64 + lane] = pk.u;
}

// ---------------- Kernel 2: sim = f f^T, LDS-FREE, L2-streaming ------------
// fb is 4 MiB (L2/L3 resident) -> load MFMA fragments DIRECTLY from global.
// No LDS, no barriers, 4 blocks/CU. Chunked XCD swizzle: adjacent bcol tiles
// share an XCD so their boundary partial cache lines merge in that L2 and
// each XCD's write window stays compact (DRAM page locality).
__global__ __launch_bounds__(256, 4) void simclr_gemm_kernel(
        const unsigned short* __restrict__ fb, float* __restrict__ out) {
    // bijective chunked swizzle: XCD x (= bid%8) owns o in [x*2048,(x+1)*2048)
    const int bid = blockIdx.x;
    const int o   = (bid & 7) * 2048 + (bid >> 3);
    const int brow = o >> 7;
    const int bcol = o & 127;

    const int tid  = threadIdx.x;
    const int lane = tid & 63;
    const int w    = tid >> 6;       // wave id 0..3
    const int wr = w >> 1, wc = w & 1;
    const int rl = lane & 15;        // fragment row index
    const int kg = lane >> 4;        // k-group

    // Per-lane base addresses (bytes). Row stride = 256 B (128 bf16).
    const char* fbb   = (const char*)fb;
    const char* abase = fbb + ((size_t)(brow * 128 + wr * 64 + rl) * 256 + kg * 16);
    const char* bbase = fbb + ((size_t)(bcol * 128 + wc * 64 + rl) * 256 + kg * 16);

    f32x4 acc[4][4];
#pragma unroll
    for (int m = 0; m < 4; ++m)
#pragma unroll
        for (int n = 0; n < 4; ++n) acc[m][n] = (f32x4){0.f, 0.f, 0.f, 0.f};

#pragma unroll
    for (int ks = 0; ks < 4; ++ks) {
        bf16x8 afr[4], bfr[4];
#pragma unroll
        for (int m = 0; m < 4; ++m)
            afr[m] = *(const bf16x8*)(abase + (size_t)m * 16 * 256 + ks * 64);
#pragma unroll
        for (int n = 0; n < 4; ++n)
            bfr[n] = *(const bf16x8*)(bbase + (size_t)n * 16 * 256 + ks * 64);
        // SWAPPED operands: lane layout of D:
        //   sim row i = brow*128 + wr*64 + m*16 + (lane&15)
        //   sim cols  = bcol*128 + wc*64 + n*16 + (lane>>4)*4 + reg
#pragma unroll
        for (int m = 0; m < 4; ++m)
#pragma unroll
            for (int n = 0; n < 4; ++n)
                acc[m][n] = __builtin_amdgcn_mfma_f32_16x16x32_bf16(bfr[n], afr[m], acc[m][n], 0, 0, 0);
    }

    // ---- fused epilogue: permute columns, store float4 per (m,n) ----
    const int i_base = brow * 128 + wr * 64 + rl;
    const int c_base = bcol * 128 + wc * 64 + (kg << 2);
#pragma unroll
    for (int m = 0; m < 4; ++m) {
        const int i = i_base + m * 16;
        const int p = i ^ B_ROWS;          // positive-pair index
        const int a = i & (B_ROWS - 1);    // min(i,p)
        const int b = a | B_ROWS;          // max(i,p)
        float* orow = out + (size_t)i * (N_TOT - 1);
#pragma unroll
        for (int n = 0; n < 4; ++n) {
            const int c = c_base + n * 16;
            f32x4 v = acc[m][n];
            // slow path only if the 4-chunk [c, c+3] contains a or b (= {i,p})
            if (__builtin_expect((unsigned)(a - c) < 4u || (unsigned)(b - c) < 4u, 0)) {
#pragma unroll
                for (int e = 0; e < 4; ++e) {
                    const int cc = c + e;
                    const float val = v[e];
                    if (cc == i) continue;                 // diagonal: dropped
                    if (cc == p) { orow[0] = val; continue; }  // positive -> col 0
                    orow[cc + 1 - (cc > a) - (cc > b)] = val;
                }
            } else {
                const int s = 1 - (c > a) - (c > b);       // uniform shift
                __builtin_memcpy(orow + c + s, &v, sizeof(v));
            }
        }
    }
}

// ---------------- Kernel 3: labels = zeros (int32 0 == fp32 0.0 bits) ------
__global__ void simclr_zero_labels(float* __restrict__ out) {
    out[(size_t)N_TOT * (N_TOT - 1) + blockIdx.x * 256 + threadIdx.x] = 0.0f;
}

extern "C" void kernel_launch(void* const* d_in, const int* in_sizes, int n_in,
                              void* d_out, int out_size, void* d_ws, size_t ws_size,
                              hipStream_t stream) {
    const float* q = (const float*)d_in[0];
    const float* k = (const float*)d_in[1];
    float* out = (float*)d_out;
    unsigned int* fb = (unsigned int*)d_ws;   // 16384*128 bf16 = 4 MiB scratch

    simclr_norm_kernel<<<N_TOT / 4, 256, 0, stream>>>(q, k, fb);
    simclr_zero_labels<<<N_TOT / 256, 256, 0, stream>>>(out);
    simclr_gemm_kernel<<<128 * 128, 256, 0, stream>>>((const unsigned short*)d_ws, out);
}

// Round 4
// 405.188 us; speedup vs baseline: 1.1267x; 1.1267x over previous
//
#include <hip/hip_runtime.h>
#include <hip/hip_bf16.h>
#include <stdint.h>

#define B_ROWS 8192
#define N_TOT  16384
#define D_DIM  128
// sqrt(1/0.07): fold temperature into the normalized features so
// (s*f_i)·(s*f_j) = sim/TEMP and the epilogue stores acc directly.
#define SCALE_SQRT_INVT 3.7796447300922722f

typedef __bf16 bf16x8 __attribute__((ext_vector_type(8)));
typedef float  f32x4  __attribute__((ext_vector_type(4)));

// ---------------- Kernel 1: normalize rows of concat(q,k) -> bf16 ----------
__global__ void simclr_norm_kernel(const float* __restrict__ q,
                                   const float* __restrict__ k,
                                   unsigned int* __restrict__ fb) {
    const int lane = threadIdx.x & 63;
    const int row  = blockIdx.x * 4 + (threadIdx.x >> 6);
    const float* src = (row < B_ROWS) ? (q + (size_t)row * D_DIM)
                                      : (k + (size_t)(row - B_ROWS) * D_DIM);
    float2 v = ((const float2*)src)[lane];
    float s = v.x * v.x + v.y * v.y;
#pragma unroll
    for (int off = 32; off > 0; off >>= 1) s += __shfl_xor(s, off);
    float rn = SCALE_SQRT_INVT / fmaxf(sqrtf(s), 1e-12f);
    union { __bf16 h[2]; unsigned int u; } pk;
    pk.h[0] = (__bf16)(v.x * rn);
    pk.h[1] = (__bf16)(v.y * rn);
    fb[(size_t)row * 64 + lane] = pk.u;
}

// ---------------- Kernel 2: sim = f f^T, row-slab version ------------------
// Each block owns 64 consecutive output rows x one 8192-col half.
// A-stripe (64 x K=128) lives in REGISTERS (loaded once). Loop over 64
// B-tiles (128 cols each) staged in 32 KB LDS (pre-swizzled source so the
// XOR-swizzled ds_read_b128 fragment reads are conflict-free).
// Writes: block covers a contiguous ~2 MB output region; adjacent 512 B
// row-segments are written by the SAME block a few K cycles apart, so
// boundary partial lines merge in the XCD's L2 -> full-line DRAM writes.
__global__ __launch_bounds__(256, 2) void simclr_gemm_kernel(
        const unsigned short* __restrict__ fb, float* __restrict__ out) {
    __shared__ char lds[32768];   // one B tile: 128 rows x 256 B

    const int bid = blockIdx.x;   // 0..511
    const int r0  = (bid >> 1) * 64;          // row-slab base
    const int h   = bid & 1;                  // column half
    const int tid  = threadIdx.x;
    const int lane = tid & 63;
    const int w    = tid >> 6;                // wave id 0..3
    const int rl = lane & 15;                 // fragment row index
    const int kg = lane >> 4;                 // k-group

    const char* fbb = (const char*)fb;

    // ---- A fragments: 64 rows x K=128 in registers (one-time L2 reads) ----
    bf16x8 afr[4][4];
#pragma unroll
    for (int m = 0; m < 4; ++m)
#pragma unroll
        for (int ks = 0; ks < 4; ++ks)
            afr[m][ks] = *(const bf16x8*)(fbb + (size_t)(r0 + m * 16 + rl) * 256 + ks * 64 + kg * 16);

    for (int t = 0; t < 64; ++t) {
        const int c0 = h * 8192 + t * 128;    // global col base of this tile

        // ---- stage B tile rows [c0, c0+128) -> LDS ----
#pragma unroll
        for (int rnd = 0; rnd < 8; ++rnd) {
            const int row   = rnd * 16 + w * 4 + (lane >> 4);
            const int chunk = (lane & 15) ^ (row & 7);     // pre-swizzle source
            const char* g = fbb + (size_t)(c0 + row) * 256 + chunk * 16;
            char* l = lds + (rnd * 16 + w * 4) * 256;      // wave-uniform base
            __builtin_amdgcn_global_load_lds((const __attribute__((address_space(1))) void*)g,
                                             (__attribute__((address_space(3))) void*)l, 16, 0, 0);
        }
        __syncthreads();

        // ---- compute: each wave does 64 rows x 32 cols (cols c0+w*32..+32) --
        f32x4 acc[4][2];
#pragma unroll
        for (int m = 0; m < 4; ++m)
#pragma unroll
            for (int n = 0; n < 2; ++n) acc[m][n] = (f32x4){0.f, 0.f, 0.f, 0.f};

#pragma unroll
        for (int ks = 0; ks < 4; ++ks) {
            const int kb = ks * 64 + kg * 16;
            bf16x8 bfr[2];
#pragma unroll
            for (int n = 0; n < 2; ++n) {
                const int rr = w * 32 + n * 16 + rl;
                bfr[n] = *(const bf16x8*)(lds + rr * 256 + (kb ^ ((rr & 7) << 4)));
            }
            // SWAPPED operands: lane layout of D:
            //   sim row i = r0 + m*16 + (lane&15)
            //   sim col c = c0 + w*32 + n*16 + (lane>>4)*4 + reg
#pragma unroll
            for (int m = 0; m < 4; ++m)
#pragma unroll
                for (int n = 0; n < 2; ++n)
                    acc[m][n] = __builtin_amdgcn_mfma_f32_16x16x32_bf16(bfr[n], afr[m][ks], acc[m][n], 0, 0, 0);
        }

        // ---- fused epilogue: permute columns, float4 stores ----
        const int cw = c0 + w * 32 + (kg << 2);
#pragma unroll
        for (int m = 0; m < 4; ++m) {
            const int i = r0 + m * 16 + rl;
            const int p = i ^ B_ROWS;          // positive-pair index
            const int a = i & (B_ROWS - 1);    // min(i,p)
            const int b = a | B_ROWS;          // max(i,p)
            float* orow = out + (size_t)i * (N_TOT - 1);
#pragma unroll
            for (int n = 0; n < 2; ++n) {
                const int c = cw + n * 16;
                f32x4 v = acc[m][n];
                // slow path only if chunk [c, c+3] contains a or b (= {i,p})
                if (__builtin_expect((unsigned)(a - c) < 4u || (unsigned)(b - c) < 4u, 0)) {
#pragma unroll
                    for (int e = 0; e < 4; ++e) {
                        const int cc = c + e;
                        const float val = v[e];
                        if (cc == i) continue;                 // diagonal: dropped
                        if (cc == p) { orow[0] = val; continue; }  // positive -> col 0
                        orow[cc + 1 - (cc > a) - (cc > b)] = val;
                    }
                } else {
                    const int s = 1 - (c > a) - (c > b);       // uniform shift
                    __builtin_memcpy(orow + c + s, &v, sizeof(v));
                }
            }
        }
        __syncthreads();
    }
}

// ---------------- Kernel 3: labels = zeros (int32 0 == fp32 0.0 bits) ------
__global__ void simclr_zero_labels(float* __restrict__ out) {
    out[(size_t)N_TOT * (N_TOT - 1) + blockIdx.x * 256 + threadIdx.x] = 0.0f;
}

extern "C" void kernel_launch(void* const* d_in, const int* in_sizes, int n_in,
                              void* d_out, int out_size, void* d_ws, size_t ws_size,
                              hipStream_t stream) {
    const float* q = (const float*)d_in[0];
    const float* k = (const float*)d_in[1];
    float* out = (float*)d_out;
    unsigned int* fb = (unsigned int*)d_ws;   // 16384*128 bf16 = 4 MiB scratch

    simclr_norm_kernel<<<N_TOT / 4, 256, 0, stream>>>(q, k, fb);
    simclr_zero_labels<<<N_TOT / 256, 256, 0, stream>>>(out);
    simclr_gemm_kernel<<<512, 256, 0, stream>>>((const unsigned short*)d_ws, out);
}

// Round 5
// 360.455 us; speedup vs baseline: 1.2665x; 1.1241x over previous
//
#include <hip/hip_runtime.h>
#include <hip/hip_bf16.h>
#include <stdint.h>

#define B_ROWS 8192
#define N_TOT  16384
#define D_DIM  128
// sqrt(1/0.07): fold temperature into the normalized features so
// (s*f_i)·(s*f_j) = sim/TEMP and the epilogue stores acc directly.
#define SCALE_SQRT_INVT 3.7796447300922722f

typedef __bf16 bf16x8 __attribute__((ext_vector_type(8)));
typedef float  f32x4  __attribute__((ext_vector_type(4)));

// ---------------- Kernel 1: normalize rows of concat(q,k) -> bf16 ----------
__global__ void simclr_norm_kernel(const float* __restrict__ q,
                                   const float* __restrict__ k,
                                   unsigned int* __restrict__ fb) {
    const int lane = threadIdx.x & 63;
    const int row  = blockIdx.x * 4 + (threadIdx.x >> 6);
    const float* src = (row < B_ROWS) ? (q + (size_t)row * D_DIM)
                                      : (k + (size_t)(row - B_ROWS) * D_DIM);
    float2 v = ((const float2*)src)[lane];
    float s = v.x * v.x + v.y * v.y;
#pragma unroll
    for (int off = 32; off > 0; off >>= 1) s += __shfl_xor(s, off);
    float rn = SCALE_SQRT_INVT / fmaxf(sqrtf(s), 1e-12f);
    union { __bf16 h[2]; unsigned int u; } pk;
    pk.h[0] = (__bf16)(v.x * rn);
    pk.h[1] = (__bf16)(v.y * rn);
    fb[(size_t)row * 64 + lane] = pk.u;
}

// ---------------- Kernel 2: sim = f f^T, row-slab + counted-vmcnt pipeline --
// Block owns 64 rows x one 8192-col half. A-stripe in registers. B tiles
// (128 cols) double-buffered in LDS. Raw s_barrier + counted s_waitcnt:
// stores are NEVER drained inside the loop (vmcnt(16) leaves 8 stores +
// 8 prefetch gloads in flight; in-order vmcnt retirement guarantees the
// current tile's 8 gloads are complete).
__global__ __launch_bounds__(256, 2) void simclr_gemm_kernel(
        const unsigned short* __restrict__ fb, float* __restrict__ out) {
    __shared__ char lds[65536];   // 2 x 32 KB B-tile double buffer

    const int bid = blockIdx.x;   // 0..511
    const int r0  = (bid >> 1) * 64;          // row-slab base
    const int h   = bid & 1;                  // column half
    const int tid  = threadIdx.x;
    const int lane = tid & 63;
    const int w    = tid >> 6;                // wave id 0..3
    const int rl = lane & 15;                 // fragment row index
    const int kg = lane >> 4;                 // k-group

    const char* fbb = (const char*)fb;

    // ---- stage one 128-row B tile (32 KB) into buffer `buf` ----
    auto stage = [&](int buf, int t) {
        const int c0 = h * 8192 + t * 128;
#pragma unroll
        for (int rnd = 0; rnd < 8; ++rnd) {
            const int row   = rnd * 16 + w * 4 + (lane >> 4);
            const int chunk = (lane & 15) ^ (row & 7);     // pre-swizzle source
            const char* g = fbb + (size_t)(c0 + row) * 256 + chunk * 16;
            char* l = lds + buf * 32768 + (rnd * 16 + w * 4) * 256;
            __builtin_amdgcn_global_load_lds((const __attribute__((address_space(1))) void*)g,
                                             (__attribute__((address_space(3))) void*)l, 16, 0, 0);
        }
    };

    stage(0, 0);   // prefetch tile 0 (8 gloads, oldest in queue)

    // ---- A fragments: 64 rows x K=128 in registers (16 global loads) ----
    bf16x8 afr[4][4];
#pragma unroll
    for (int m = 0; m < 4; ++m)
#pragma unroll
        for (int ks = 0; ks < 4; ++ks)
            afr[m][ks] = *(const bf16x8*)(fbb + (size_t)(r0 + m * 16 + rl) * 256 + ks * 64 + kg * 16);

    for (int t = 0; t < 64; ++t) {
        const int cur = t & 1;

        if (t < 63) {
            stage(cur ^ 1, t + 1);   // prefetch next tile into other buffer
            // queue suffix: [stores(t-1) x8][gload(t+1) x8] -> <=16 outstanding
            // guarantees gload(t) retired; stores stay in flight.
            asm volatile("s_waitcnt vmcnt(16)" ::: "memory");
        } else {
            asm volatile("s_waitcnt vmcnt(8)" ::: "memory");
        }
        __builtin_amdgcn_sched_barrier(0);
        __builtin_amdgcn_s_barrier();            // buf[cur] ready for all waves
        __builtin_amdgcn_sched_barrier(0);

        // ---- read all 8 B fragments for this tile into registers ----
        bf16x8 bfr[4][2];
#pragma unroll
        for (int ks = 0; ks < 4; ++ks) {
            const int kb = ks * 64 + kg * 16;
#pragma unroll
            for (int n = 0; n < 2; ++n) {
                const int rr = w * 32 + n * 16 + rl;
                bfr[ks][n] = *(const bf16x8*)(lds + cur * 32768 + rr * 256 + (kb ^ ((rr & 7) << 4)));
            }
        }
        asm volatile("s_waitcnt lgkmcnt(0)" ::: "memory");
        __builtin_amdgcn_sched_barrier(0);
        __builtin_amdgcn_s_barrier();            // buf[cur] free for next stage
        __builtin_amdgcn_sched_barrier(0);

        // ---- MFMA: 64 rows x 32 cols per wave ----
        f32x4 acc[4][2];
#pragma unroll
        for (int m = 0; m < 4; ++m)
#pragma unroll
            for (int n = 0; n < 2; ++n) acc[m][n] = (f32x4){0.f, 0.f, 0.f, 0.f};
#pragma unroll
        for (int ks = 0; ks < 4; ++ks)
#pragma unroll
            for (int m = 0; m < 4; ++m)
#pragma unroll
                for (int n = 0; n < 2; ++n)
                    acc[m][n] = __builtin_amdgcn_mfma_f32_16x16x32_bf16(bfr[ks][n], afr[m][ks], acc[m][n], 0, 0, 0);

        // ---- fused epilogue: permute columns, 8 float4 stores/thread ----
        const int c0 = h * 8192 + t * 128;
        const int cw = c0 + w * 32 + (kg << 2);
#pragma unroll
        for (int m = 0; m < 4; ++m) {
            const int i = r0 + m * 16 + rl;
            const int p = i ^ B_ROWS;          // positive-pair index
            const int a = i & (B_ROWS - 1);    // min(i,p)
            const int b = a | B_ROWS;          // max(i,p)
            float* orow = out + (size_t)i * (N_TOT - 1);
#pragma unroll
            for (int n = 0; n < 2; ++n) {
                const int c = cw + n * 16;
                f32x4 v = acc[m][n];
                // slow path only if chunk [c, c+3] contains a or b (= {i,p})
                if (__builtin_expect((unsigned)(a - c) < 4u || (unsigned)(b - c) < 4u, 0)) {
#pragma unroll
                    for (int e = 0; e < 4; ++e) {
                        const int cc = c + e;
                        const float val = v[e];
                        if (cc == i) continue;                 // diagonal: dropped
                        if (cc == p) { orow[0] = val; continue; }  // positive -> col 0
                        orow[cc + 1 - (cc > a) - (cc > b)] = val;
                    }
                } else {
                    const int s = 1 - (c > a) - (c > b);       // uniform shift
                    __builtin_memcpy(orow + c + s, &v, sizeof(v));
                }
            }
        }
    }
}

// ---------------- Kernel 3: labels = zeros (int32 0 == fp32 0.0 bits) ------
__global__ void simclr_zero_labels(float* __restrict__ out) {
    out[(size_t)N_TOT * (N_TOT - 1) + blockIdx.x * 256 + threadIdx.x] = 0.0f;
}

extern "C" void kernel_launch(void* const* d_in, const int* in_sizes, int n_in,
                              void* d_out, int out_size, void* d_ws, size_t ws_size,
                              hipStream_t stream) {
    const float* q = (const float*)d_in[0];
    const float* k = (const float*)d_in[1];
    float* out = (float*)d_out;
    unsigned int* fb = (unsigned int*)d_ws;   // 16384*128 bf16 = 4 MiB scratch

    simclr_norm_kernel<<<N_TOT / 4, 256, 0, stream>>>(q, k, fb);
    simclr_zero_labels<<<N_TOT / 256, 256, 0, stream>>>(out);
    simclr_gemm_kernel<<<512, 256, 0, stream>>>((const unsigned short*)d_ws, out);
}